// Round 6
// baseline (120.658 us; speedup 1.0000x reference)
//
#include <hip/hip_runtime.h>
#include <hip/hip_bf16.h>
#include <stdint.h>
#include <stddef.h>

// NT-Xent loss, B=4096, D=256, N=8192, T=0.5.
// normalize(+zero sumexp) -> fused symmetric ZZ^T GEMM + exp row/col-sum +
// positive capture -> 1-block finalize/mean. No NxN materialization.
//
// R13: DEFERRED-EPILOGUE PIPELINE. R12 (92.5 us, simexp ~33) is bound by
// the per-tile exp/sum epilogue (~2640 cyc/tile/CU > MFMA's 2483): it runs
// between barriers with the matrix pipe idle. Same-tile overlap impossible
// (full-D accumulate), so defer by ONE tile: tile t's 4 MFMA phases carry
// tile t-1's epilogue in 4 slices (ti quarter per phase, placed after the
// phase's MFMA cluster; slice reads only prev acc -> co-issues on VALU
// while matrix pipe drains). acc double-buffered (accA/accB, static names
// per rule #20, pair-loop 2 bodies); prev colsum partials in 2 scalars;
// colsum reduce+atomics at tile boundary (4 phases older than the next
// vmcnt(0) -> no stall). Tail + final tile-7 epilogue serial as before.
// Carry-overs: R12 8-wave 128x128 4-phase schedule (vmcnt(0) once per
// tile), A-bounce through LDS (af[4][8] pinned), XOR-swizzled LDS,
// symmetry (2080 tile-pairs), exp-scale folded into normalize.

#define B_ROWS 4096
#define D_DIM  256
#define N_ROWS 8192
#define BM 128
#define BN 128

typedef __bf16 bf16;
typedef bf16  bf16x8  __attribute__((ext_vector_type(8)));
typedef bf16  bf16x4  __attribute__((ext_vector_type(4)));
typedef float floatx4 __attribute__((ext_vector_type(4)));

// ---------------------------------------------------------------- normalize
// One wave per row: 256 fp32 -> L2-normalized bf16, pre-scaled by
// sqrt(2/ln2) so dot' = (2/ln2)*dot and e = exp2(dot'). Zeroes sumexp.
__global__ __launch_bounds__(256) void normalize_kernel(
    const float* __restrict__ z_i, const float* __restrict__ z_j,
    bf16* __restrict__ zn, float* __restrict__ sumexp) {
  const int wave = threadIdx.x >> 6;
  const int lane = threadIdx.x & 63;
  const int row  = blockIdx.x * 4 + wave;
  const float* src = (row < B_ROWS) ? (z_i + (size_t)row * D_DIM)
                                    : (z_j + (size_t)(row - B_ROWS) * D_DIM);
  float4 v = ((const float4*)src)[lane];
  float ss = v.x * v.x + v.y * v.y + v.z * v.z + v.w * v.w;
  #pragma unroll
  for (int m = 1; m < 64; m <<= 1) ss += __shfl_xor(ss, m);
  const float rn = rsqrtf(ss) * 1.6986436f;  // * sqrt(2/ln2)
  bf16x4 o;
  o[0] = (bf16)(v.x * rn);
  o[1] = (bf16)(v.y * rn);
  o[2] = (bf16)(v.z * rn);
  o[3] = (bf16)(v.w * rn);
  ((bf16x4*)(zn + (size_t)row * D_DIM))[lane] = o;
  if (lane == 0) sumexp[row] = 0.f;
}

// ------------------------------------------------------- fused sim+exp+sum
// Grid: 64 ri x 4 cj = 256 blocks (1/CU). Block (ri,cj): 8 tiles s=8cj+t;
// blocks (ri<32, cj>=2) add the j64-half (cj-2) of the s=32 tile (tail).
// 8 waves in 2x4; wave = 64 rows x 32 cols = 4x2 frags of 16x16x32 bf16
// MFMA, full-D accumulate. LDS XOR-swizzled, swizzle on the global source.
__global__ __launch_bounds__(512, 2) void simexp_kernel(
    const bf16* __restrict__ zn, float* __restrict__ sumexp,
    float* __restrict__ pos) {
  __shared__ __align__(16) bf16 Bs[2][BN * D_DIM];  // 2 x 64 KB

  const int tid   = threadIdx.x;
  const int wave  = tid >> 6;
  const int lane  = tid & 63;
  const int lcol  = lane & 15;   // MFMA: A row / B col / C col
  const int lquad = lane >> 4;   // MFMA: k-group / C row-group
  const int wr = (wave >> 2) * 64;  // wave row offset in 128
  const int wc = (wave & 3) * 32;   // wave col offset in 128
  const int ri = blockIdx.x >> 2;   // row tile 0..63
  const int cj = blockIdx.x & 3;    // s-chunk 0..3
  const int row_base = ri * BM;
  const bool has_tail = (ri < 32 && cj >= 2);

  auto ct_of = [&](int t) { return (ri + 8 * cj + t) & 63; };  // col tile

  // stage rows of a tile into Bs[buf]: chunk slot s=it*512+tid, row n=s>>5,
  // swizzled k-chunk kc; 16B global_load_lds, coalesced, source-swizzled.
  auto stageB = [&](int buf, const bf16* src, int it0, int it1) {
    for (int it = it0; it < it1; ++it) {
      const int s   = it * 512 + tid;
      const int n   = s >> 5;
      const int kcs = s & 31;
      const int kc  = (kcs & 24) | ((kcs & 7) ^ (n & 7));
      __builtin_amdgcn_global_load_lds(
          (const __attribute__((address_space(1))) unsigned int*)
              (src + (size_t)n * D_DIM + kc * 8),
          (__attribute__((address_space(3))) unsigned int*)&Bs[buf][s * 8],
          16, 0, 0);
    }
  };

  // ---- prologue: A tile -> buf0, first B tile -> buf1, overlapped.
  stageB(0, zn + (size_t)row_base * D_DIM, 0, 8);
  stageB(1, zn + (size_t)ct_of(0) * BM * D_DIM, 0, 8);
  __syncthreads();  // drains vmcnt(0): both tiles resident

  // af[ti][kq] from buf0 (backing later overwritten -> pinned in regs).
  floatx4 af[4][8];
  #pragma unroll
  for (int ti = 0; ti < 4; ++ti) {
    const int n = wr + ti * 16 + lcol;
    #pragma unroll
    for (int kq = 0; kq < 8; ++kq) {
      const int kc  = kq * 4 + lquad;
      const int kcs = (kc & 24) | ((kc & 7) ^ (n & 7));
      af[ti][kq] = *(const floatx4*)(&Bs[0][(n * 32 + kcs) * 8]);
    }
  }
  __syncthreads();  // all af reads done -> buf0 free for staging

  float rowsum[4][4];  // [ti][r]; row = wr + ti*16 + lquad*4 + r
  #pragma unroll
  for (int ti = 0; ti < 4; ++ti)
    #pragma unroll
    for (int r = 0; r < 4; ++r) rowsum[ti][r] = 0.f;

  floatx4 accA[4][2], accB[4][2];     // double-buffered accumulators
  float pcs0 = 0.f, pcs1 = 0.f;       // prev-tile colsum partials (tj 0/1)
  int   pcol  = 0;                    // prev-tile col_base
  bool  pdiag = false;                // prev tile is the s=0 diag tile

#define MFMA_(A, B_, C) __builtin_amdgcn_mfma_f32_16x16x32_bf16( \
    __builtin_bit_cast(bf16x8, A), B_, C, 0, 0, 0)

  // one ti-quarter of the PREV tile's epilogue (exp + row/col sums)
#define SLICE(ACCP, TI, PV)                                               \
    if (PV) {                                                             \
      _Pragma("unroll")                                                   \
      for (int tj = 0; tj < 2; ++tj) {                                    \
        _Pragma("unroll")                                                 \
        for (int r = 0; r < 4; ++r) {                                     \
          const float v = ACCP[TI][tj][r];                                \
          float e = __builtin_amdgcn_exp2f(v);                            \
          if (pdiag) {                                                    \
            const int rg = row_base + wr + (TI) * 16 + lquad * 4 + r;     \
            const int cg = pcol + wc + tj * 16 + lcol;                    \
            if (cg == rg) e = 0.f;  /* mask self-similarity */            \
          }                                                               \
          rowsum[TI][r] += e;                                             \
          if (tj == 0) pcs0 += e; else pcs1 += e;                         \
        }                                                                 \
      }                                                                   \
    }

#define PHASE(ACCC, ACCP, PV, KQA, KQB, IT0, IT1, DO_VM, TI)              \
  {                                                                       \
    bf16x8 bfrA[2], bfrB[2];                                              \
    const int kcA = (KQA) * 4 + lquad, kcB = (KQB) * 4 + lquad;           \
    _Pragma("unroll")                                                     \
    for (int tj = 0; tj < 2; ++tj) {                                      \
      const int n  = wc + tj * 16 + lcol;                                 \
      const int sA = (kcA & 24) | ((kcA & 7) ^ (n & 7));                  \
      const int sB = (kcB & 24) | ((kcB & 7) ^ (n & 7));                  \
      bfrA[tj] = *(const bf16x8*)(bbase + n * D_DIM + sA * 8);            \
      bfrB[tj] = *(const bf16x8*)(bbase + n * D_DIM + sB * 8);            \
    }                                                                     \
    stageB(sb, nsrc, IT0, IT1);                                           \
    __builtin_amdgcn_sched_barrier(0);                                    \
    __builtin_amdgcn_s_barrier();                                         \
    asm volatile("s_waitcnt lgkmcnt(0)" ::: "memory");                    \
    __builtin_amdgcn_sched_barrier(0);                                    \
    __builtin_amdgcn_s_setprio(1);                                        \
    _Pragma("unroll")                                                     \
    for (int ti = 0; ti < 4; ++ti) {                                      \
      ACCC[ti][0] = MFMA_(af[ti][KQA], bfrA[0], ACCC[ti][0]);             \
      ACCC[ti][1] = MFMA_(af[ti][KQA], bfrA[1], ACCC[ti][1]);             \
    }                                                                     \
    _Pragma("unroll")                                                     \
    for (int ti = 0; ti < 4; ++ti) {                                      \
      ACCC[ti][0] = MFMA_(af[ti][KQB], bfrB[0], ACCC[ti][0]);             \
      ACCC[ti][1] = MFMA_(af[ti][KQB], bfrB[1], ACCC[ti][1]);             \
    }                                                                     \
    __builtin_amdgcn_s_setprio(0);                                        \
    SLICE(ACCP, TI, PV)  /* prev-tile epilogue quarter, hides under MFMA */\
    if (DO_VM) asm volatile("s_waitcnt vmcnt(0)" ::: "memory");           \
    __builtin_amdgcn_sched_barrier(0);                                    \
    __builtin_amdgcn_s_barrier();                                         \
  }

  // full tile: 4 phases + prev colsum flush + save this tile's meta
#define TILE_BODY(ACCC, ACCP, PV, CB, TT)                                 \
  {                                                                       \
    const int sb = (CB) ^ 1;                                              \
    const bf16* bbase = &Bs[CB][0];                                       \
    const bf16* nsrc = nullptr;                                           \
    int nl = 0;                                                           \
    if ((TT) < 7) {                                                       \
      nsrc = zn + (size_t)ct_of((TT) + 1) * BM * D_DIM;                   \
      nl = 8;                                                             \
    } else if (has_tail) {                                                \
      nsrc = zn + (size_t)((ri + 32) * BM + (cj - 2) * 64) * D_DIM;       \
      nl = 4;                                                             \
    }                                                                     \
    const int nh = nl >> 1;                                               \
    _Pragma("unroll")                                                     \
    for (int ti = 0; ti < 4; ++ti) {                                      \
      ACCC[ti][0] = floatx4{0.f, 0.f, 0.f, 0.f};                          \
      ACCC[ti][1] = floatx4{0.f, 0.f, 0.f, 0.f};                          \
    }                                                                     \
    PHASE(ACCC, ACCP, PV, 0, 1, 0, nh, false, 0)                          \
    PHASE(ACCC, ACCP, PV, 2, 3, nh, nl, false, 1)                         \
    PHASE(ACCC, ACCP, PV, 4, 5, 0, 0, false, 2)                           \
    PHASE(ACCC, ACCP, PV, 6, 7, 0, 0, true, 3)                            \
    if ((PV) && !pdiag) { /* prev colsums -> partner-tile rows */         \
      float c0 = pcs0, c1 = pcs1;                                         \
      c0 += __shfl_xor(c0, 16); c0 += __shfl_xor(c0, 32);                 \
      c1 += __shfl_xor(c1, 16); c1 += __shfl_xor(c1, 32);                 \
      if (lquad == 0) {                                                   \
        atomicAdd(&sumexp[pcol + wc + lcol], c0);                         \
        atomicAdd(&sumexp[pcol + wc + 16 + lcol], c1);                    \
      }                                                                   \
    }                                                                     \
    pcol = ct_of(TT) * BM;                                                \
    pdiag = (cj == 0 && (TT) == 0);                                       \
    pcs0 = 0.f; pcs1 = 0.f;                                               \
  }

  #pragma unroll 1  // one pair-body copy (I$)
  for (int t = 0; t < 8; t += 2) {
    TILE_BODY(accA, accB, (t > 0), 1, t)      // even tile: compute buf1
    TILE_BODY(accB, accA, true, 0, t + 1)     // odd tile: compute buf0
  }

  // ---- final epilogue: tile 7 (accB; never diag) ----
  {
    float c0 = 0.f, c1 = 0.f;
    #pragma unroll
    for (int ti = 0; ti < 4; ++ti)
      #pragma unroll
      for (int tj = 0; tj < 2; ++tj)
        #pragma unroll
        for (int r = 0; r < 4; ++r) {
          const float e = __builtin_amdgcn_exp2f(accB[ti][tj][r]);
          rowsum[ti][r] += e;
          if (tj == 0) c0 += e; else c1 += e;
        }
    c0 += __shfl_xor(c0, 16); c0 += __shfl_xor(c0, 32);
    c1 += __shfl_xor(c1, 16); c1 += __shfl_xor(c1, 32);
    if (lquad == 0) {
      atomicAdd(&sumexp[pcol + wc + lcol], c0);
      atomicAdd(&sumexp[pcol + wc + 16 + lcol], c1);
    }
  }

  // ---- tail: j64-half (cj-2) of the s=32 tile, buf1 (staged during tile
  // 7, drained by its phase-4 vmcnt(0)+barrier; never rewritten). Positive
  // pairs live exactly here: cg == rg + B_ROWS.
  if (has_tail && wc < 64) {
    const int col_base = (ri + 32) * BM + (cj - 2) * 64;
    const bf16* bbase = &Bs[1][0];
    floatx4 acc[4][2];
    #pragma unroll
    for (int ti = 0; ti < 4; ++ti)
      #pragma unroll
      for (int tj = 0; tj < 2; ++tj) acc[ti][tj] = floatx4{0.f, 0.f, 0.f, 0.f};
    #pragma unroll
    for (int kq = 0; kq < 8; ++kq) {
      const int kc = kq * 4 + lquad;
      bf16x8 bfr[2];
      #pragma unroll
      for (int tj = 0; tj < 2; ++tj) {
        const int n   = wc + tj * 16 + lcol;  // 0..63: staged rows
        const int kcs = (kc & 24) | ((kc & 7) ^ (n & 7));
        bfr[tj] = *(const bf16x8*)(bbase + n * D_DIM + kcs * 8);
      }
      #pragma unroll
      for (int ti = 0; ti < 4; ++ti) {
        acc[ti][0] = MFMA_(af[ti][kq], bfr[0], acc[ti][0]);
        acc[ti][1] = MFMA_(af[ti][kq], bfr[1], acc[ti][1]);
      }
    }
    float c0 = 0.f, c1 = 0.f;
    #pragma unroll
    for (int ti = 0; ti < 4; ++ti) {
      #pragma unroll
      for (int tj = 0; tj < 2; ++tj) {
        #pragma unroll
        for (int r = 0; r < 4; ++r) {
          const float v = acc[ti][tj][r];
          const float e = __builtin_amdgcn_exp2f(v);
          const int rg = row_base + wr + ti * 16 + lquad * 4 + r;
          const int cg = col_base + wc + tj * 16 + lcol;
          if (cg == rg + B_ROWS) {               // positive pair
            const float p = v * 0.6931471805599453f;  // sim/T = v*ln2
            pos[rg] = p;
            pos[cg] = p;
          }
          rowsum[ti][r] += e;
          if (tj == 0) c0 += e; else c1 += e;
        }
      }
    }
    c0 += __shfl_xor(c0, 16); c0 += __shfl_xor(c0, 32);
    c1 += __shfl_xor(c1, 16); c1 += __shfl_xor(c1, 32);
    if (lquad == 0) {
      atomicAdd(&sumexp[col_base + wc + lcol], c0);
      atomicAdd(&sumexp[col_base + wc + 16 + lcol], c1);
    }
  }
#undef TILE_BODY
#undef PHASE
#undef SLICE
#undef MFMA_

  // reduce the 16 col-lanes of rowsum, then 1 atomic per row per wave
  #pragma unroll
  for (int ti = 0; ti < 4; ++ti) {
    #pragma unroll
    for (int r = 0; r < 4; ++r) {
      float s2 = rowsum[ti][r];
      s2 += __shfl_xor(s2, 1);
      s2 += __shfl_xor(s2, 2);
      s2 += __shfl_xor(s2, 4);
      s2 += __shfl_xor(s2, 8);
      if (lcol == 0) {
        const int grow = row_base + wr + ti * 16 + lquad * 4 + r;
        atomicAdd(&sumexp[grow], s2);
      }
    }
  }
}

// ------------------------------------------------- finalize + mean (1 block)
// loss_i = log(sumexp_i) - pos_i ; out = mean(loss)
__global__ __launch_bounds__(1024) void reduce_kernel(
    const float* __restrict__ sumexp, const float* __restrict__ pos,
    float* __restrict__ out) {
  __shared__ float ws[16];
  const int tid = threadIdx.x;
  float s = 0.f;
  const float ln2 = 0.6931471805599453f;
  for (int k = tid; k < N_ROWS; k += 1024)
    s += __builtin_amdgcn_logf(sumexp[k]) * ln2 - pos[k];
  #pragma unroll
  for (int m = 1; m < 64; m <<= 1) s += __shfl_xor(s, m);
  const int wave = tid >> 6, lane = tid & 63;
  if (lane == 0) ws[wave] = s;
  __syncthreads();
  if (wave == 0) {
    float t = (lane < 16) ? ws[lane] : 0.f;
    #pragma unroll
    for (int m = 1; m < 16; m <<= 1) t += __shfl_xor(t, m);
    if (lane == 0) out[0] = t * (1.0f / N_ROWS);
  }
}

extern "C" void kernel_launch(void* const* d_in, const int* in_sizes, int n_in,
                              void* d_out, int out_size, void* d_ws,
                              size_t ws_size, hipStream_t stream) {
  const float* z_i = (const float*)d_in[0];
  const float* z_j = (const float*)d_in[1];
  float* out = (float*)d_out;

  // workspace layout: zn (4 MB bf16) | sumexp (32 KB) | pos (32 KB)
  bf16* zn = (bf16*)d_ws;
  float* sumexp = (float*)((char*)d_ws + (size_t)N_ROWS * D_DIM * sizeof(bf16));
  float* pos = sumexp + N_ROWS;

  normalize_kernel<<<N_ROWS / 4, 256, 0, stream>>>(z_i, z_j, zn, sumexp);
  simexp_kernel<<<256, 512, 0, stream>>>(zn, sumexp, pos);
  reduce_kernel<<<1, 1024, 0, stream>>>(sumexp, pos, out);
}

// Round 7
// 92.081 us; speedup vs baseline: 1.3103x; 1.3103x over previous
//
#include <hip/hip_runtime.h>
#include <hip/hip_bf16.h>
#include <stdint.h>
#include <stddef.h>

// NT-Xent loss, B=4096, D=256, N=8192, T=0.5.
// normalize(+zero sumexp) -> fused symmetric ZZ^T GEMM + exp row/col-sum +
// positive capture -> 1-block finalize/mean. No NxN materialization.
//
// R14: FIT IN 128 VGPRs + QUADRANT-PHASE OVERLAP. R13 proved the allocator
// caps this kernel at 128 arch VGPRs and spills anything bigger (VGPR=128,
// FETCH 109 MB of scratch traffic, 60 us). Redesign within the budget:
//  (a) 4x2 wave geometry (wave = 32 rows x 64 cols): af[2][8] = 64 VGPRs.
//  (b) phase = ONE tj-quadrant (16 cols) over FULL K (16 MFMA): quadrant
//      acc (8 regs) is final at phase end -> its exp/rowsum/colsum slice
//      runs during the NEXT quadrant's MFMAs (same tile, no acc dbuf;
//      only q3's slice defers one tile = 8 carried regs).
//  (c) ONE __syncthreads per tile (was 8 barriers): reads hit buf[cur],
//      staging writes buf[cur^1] - disjoint; waves free-run 4 phases ->
//      cross-wave MFMA/LDS/VALU overlap; compiler's lgkmcnt handles
//      ds_read->MFMA ordering.
// Carry-overs: A-bounce through LDS (stage A->buf0, read af, reuse buf),
// XOR-swizzled conflict-free LDS (swizzle on global source), symmetry
// (2080 unordered 128x128 tile-pairs; row-sums to rows(ri), col-sums to
// rows(ct); diag s=0 row-only), balanced tail (s=32 halves on cj2/cj3),
// exp-scale folded into normalize (e = exp2(dot'), pos = dot'*ln2).

#define B_ROWS 4096
#define D_DIM  256
#define N_ROWS 8192
#define BM 128
#define BN 128

typedef __bf16 bf16;
typedef bf16  bf16x8  __attribute__((ext_vector_type(8)));
typedef bf16  bf16x4  __attribute__((ext_vector_type(4)));
typedef float floatx4 __attribute__((ext_vector_type(4)));

// ---------------------------------------------------------------- normalize
// One wave per row: 256 fp32 -> L2-normalized bf16, pre-scaled by
// sqrt(2/ln2) so dot' = (2/ln2)*dot and e = exp2(dot'). Zeroes sumexp.
__global__ __launch_bounds__(256) void normalize_kernel(
    const float* __restrict__ z_i, const float* __restrict__ z_j,
    bf16* __restrict__ zn, float* __restrict__ sumexp) {
  const int wave = threadIdx.x >> 6;
  const int lane = threadIdx.x & 63;
  const int row  = blockIdx.x * 4 + wave;
  const float* src = (row < B_ROWS) ? (z_i + (size_t)row * D_DIM)
                                    : (z_j + (size_t)(row - B_ROWS) * D_DIM);
  float4 v = ((const float4*)src)[lane];
  float ss = v.x * v.x + v.y * v.y + v.z * v.z + v.w * v.w;
  #pragma unroll
  for (int m = 1; m < 64; m <<= 1) ss += __shfl_xor(ss, m);
  const float rn = rsqrtf(ss) * 1.6986436f;  // * sqrt(2/ln2)
  bf16x4 o;
  o[0] = (bf16)(v.x * rn);
  o[1] = (bf16)(v.y * rn);
  o[2] = (bf16)(v.z * rn);
  o[3] = (bf16)(v.w * rn);
  ((bf16x4*)(zn + (size_t)row * D_DIM))[lane] = o;
  if (lane == 0) sumexp[row] = 0.f;
}

// ------------------------------------------------------- fused sim+exp+sum
// Grid: 64 ri x 4 cj = 256 blocks (1/CU, 128 KB LDS). Block (ri,cj): 8
// tiles s=8cj+t; blocks (ri<32, cj>=2) add the j64-half (cj-2) of s=32.
// 8 waves in 4x2 (wave = 32 rows x 64 cols); phase = one 16-col quadrant
// x full K = 16 MFMA of 16x16x32 bf16.
__global__ __launch_bounds__(512, 2) void simexp_kernel(
    const bf16* __restrict__ zn, float* __restrict__ sumexp,
    float* __restrict__ pos) {
  __shared__ __align__(16) bf16 Bs[2][BN * D_DIM];  // 2 x 64 KB

  const int tid   = threadIdx.x;
  const int wave  = tid >> 6;
  const int lane  = tid & 63;
  const int lcol  = lane & 15;   // MFMA: A row / B col / C col
  const int lquad = lane >> 4;   // MFMA: k-group / C row-group
  const int wr = (wave >> 1) * 32;  // wave row offset: 0,32,64,96
  const int wc = (wave & 1) * 64;   // wave col offset: 0,64
  const int ri = blockIdx.x >> 2;   // row tile 0..63
  const int cj = blockIdx.x & 3;    // s-chunk 0..3
  const int row_base = ri * BM;
  const bool has_tail = (ri < 32 && cj >= 2);

  auto ct_of = [&](int t) { return (ri + 8 * cj + t) & 63; };  // col tile

  // stage rows [16*it0, 16*it1) of a 128-row tile into Bs[buf]: chunk slot
  // s=it*512+tid, row n=s>>5, swizzled k-chunk; coalesced 16B loads,
  // swizzle applied on the GLOBAL source address (LDS dest linear).
  auto stageB = [&](int buf, const bf16* src, int it0, int it1) {
    for (int it = it0; it < it1; ++it) {
      const int s   = it * 512 + tid;
      const int n   = s >> 5;
      const int kcs = s & 31;
      const int kc  = (kcs & 24) | ((kcs & 7) ^ (n & 7));
      __builtin_amdgcn_global_load_lds(
          (const __attribute__((address_space(1))) unsigned int*)
              (src + (size_t)n * D_DIM + kc * 8),
          (__attribute__((address_space(3))) unsigned int*)&Bs[buf][s * 8],
          16, 0, 0);
    }
  };

  // ---- prologue: A tile -> buf0, first B tile -> buf1, overlapped.
  stageB(0, zn + (size_t)row_base * D_DIM, 0, 8);
  stageB(1, zn + (size_t)ct_of(0) * BM * D_DIM, 0, 8);
  __syncthreads();  // vmcnt(0): both tiles resident

  // af[ti][kq]: row = row_base+wr+ti*16+lcol, k = kq*32+lquad*8..+7.
  // buf0's backing is overwritten below -> af MUST live in registers (64).
  floatx4 af[2][8];
  #pragma unroll
  for (int ti = 0; ti < 2; ++ti) {
    const int n = wr + ti * 16 + lcol;
    #pragma unroll
    for (int kq = 0; kq < 8; ++kq) {
      const int kc  = kq * 4 + lquad;
      const int kcs = (kc & 24) | ((kc & 7) ^ (n & 7));
      af[ti][kq] = *(const floatx4*)(&Bs[0][(n * 32 + kcs) * 8]);
    }
  }
  __syncthreads();  // af reads done -> buf0 free for staging

  float rowsum[2][4];  // [ti][r]; row = wr + ti*16 + lquad*4 + r
  #pragma unroll
  for (int ti = 0; ti < 2; ++ti)
    #pragma unroll
    for (int r = 0; r < 4; ++r) rowsum[ti][r] = 0.f;

#define MFMA_(A, B_, C) __builtin_amdgcn_mfma_f32_16x16x32_bf16( \
    __builtin_bit_cast(bf16x8, A), B_, C, 0, 0, 0)

  // one quadrant: read 8 B frags (col group wc+Q*16), 16 MFMA over full K
#define QPHASE(ACC, Q)                                                    \
  {                                                                       \
    bf16x8 bfr[8];                                                        \
    const int n = wc + (Q) * 16 + lcol;                                   \
    _Pragma("unroll")                                                     \
    for (int kq = 0; kq < 8; ++kq) {                                      \
      const int kc  = kq * 4 + lquad;                                     \
      const int kcs = (kc & 24) | ((kc & 7) ^ (n & 7));                   \
      bfr[kq] = *(const bf16x8*)(bbase + n * D_DIM + kcs * 8);            \
    }                                                                     \
    ACC[0] = floatx4{0.f, 0.f, 0.f, 0.f};                                 \
    ACC[1] = floatx4{0.f, 0.f, 0.f, 0.f};                                 \
    _Pragma("unroll")                                                     \
    for (int kq = 0; kq < 8; ++kq) {                                      \
      ACC[0] = MFMA_(af[0][kq], bfr[kq], ACC[0]);                         \
      ACC[1] = MFMA_(af[1][kq], bfr[kq], ACC[1]);                         \
    }                                                                     \
  }

  // epilogue slice for a finished quadrant: exp + rowsum + colsum+atomic
#define SLICE(ACC, Q, CB, DG)                                             \
  {                                                                       \
    float cs = 0.f;                                                       \
    _Pragma("unroll")                                                     \
    for (int ti = 0; ti < 2; ++ti) {                                      \
      _Pragma("unroll")                                                   \
      for (int r = 0; r < 4; ++r) {                                       \
        const float v = ACC[ti][r];                                       \
        float e = __builtin_amdgcn_exp2f(v);                              \
        if (DG) {                                                         \
          const int rg = row_base + wr + ti * 16 + lquad * 4 + r;         \
          const int cg = (CB) + wc + (Q) * 16 + lcol;                     \
          if (cg == rg) e = 0.f;  /* mask self-similarity */              \
        }                                                                 \
        rowsum[ti][r] += e;                                               \
        cs += e;                                                          \
      }                                                                   \
    }                                                                     \
    cs += __shfl_xor(cs, 16);                                             \
    cs += __shfl_xor(cs, 32);                                             \
    if (!(DG) && lquad == 0)                                              \
      atomicAdd(&sumexp[(CB) + wc + (Q) * 16 + lcol], cs);                \
  }

  floatx4 a3[2];            // q3 acc, carried one tile (sliced next tile)
  int  pcol3  = 0;
  bool pdiag3 = false;

  #pragma unroll 1  // one body copy (I$); single barrier per tile
  for (int t = 0; t < 8; ++t) {
    const bf16* bbase = &Bs[(t + 1) & 1][0];   // compute buffer
    const int sb = t & 1;                      // stage buffer (disjoint)
    if (t < 7) {
      stageB(sb, zn + (size_t)ct_of(t + 1) * BM * D_DIM, 0, 8);
    } else if (has_tail) {
      stageB(sb, zn + (size_t)((ri + 32) * BM + (cj - 2) * 64) * D_DIM, 0, 4);
    }
    const int  colb = ct_of(t) * BM;
    const bool diag = (cj == 0 && t == 0);

    floatx4 a0[2], a1[2], a2[2];
    QPHASE(a0, 0)
    if (t > 0) SLICE(a3, 3, pcol3, pdiag3)   // prev tile's q3, overlapped
    QPHASE(a1, 1)
    SLICE(a0, 0, colb, diag)
    QPHASE(a2, 2)
    SLICE(a1, 1, colb, diag)
    QPHASE(a3, 3)
    SLICE(a2, 2, colb, diag)
    pcol3 = colb;
    pdiag3 = diag;
    __syncthreads();  // vmcnt(0)+barrier: stage done, buffer swap safe
  }
  SLICE(a3, 3, pcol3, pdiag3)   // tile 7's q3

  // ---- tail: j64-half (cj-2) of the s=32 tile, in buf1 (staged during
  // tile 7, drained by its __syncthreads; never rewritten). Positive pairs
  // live exactly here: cg == rg + B_ROWS. 4 waves (wc==0) cover 128x64.
  if (has_tail && wc == 0) {
    const int colb = (ri + 32) * BM + (cj - 2) * 64;
    const bf16* bbase = &Bs[1][0];
    floatx4 ta[2];
    #pragma unroll
    for (int Q = 0; Q < 4; ++Q) {
      QPHASE(ta, Q)
      float cs = 0.f;
      #pragma unroll
      for (int ti = 0; ti < 2; ++ti) {
        #pragma unroll
        for (int r = 0; r < 4; ++r) {
          const float v = ta[ti][r];
          const float e = __builtin_amdgcn_exp2f(v);
          const int rg = row_base + wr + ti * 16 + lquad * 4 + r;
          const int cg = colb + Q * 16 + lcol;
          if (cg == rg + B_ROWS) {                    // positive pair
            const float p = v * 0.6931471805599453f;  // sim/T = v*ln2
            pos[rg] = p;
            pos[cg] = p;
          }
          rowsum[ti][r] += e;
          cs += e;
        }
      }
      cs += __shfl_xor(cs, 16);
      cs += __shfl_xor(cs, 32);
      if (lquad == 0) atomicAdd(&sumexp[colb + Q * 16 + lcol], cs);
    }
  }
#undef SLICE
#undef QPHASE
#undef MFMA_

  // reduce the 16 col-lanes of rowsum, then 1 atomic per row per wave
  #pragma unroll
  for (int ti = 0; ti < 2; ++ti) {
    #pragma unroll
    for (int r = 0; r < 4; ++r) {
      float s2 = rowsum[ti][r];
      s2 += __shfl_xor(s2, 1);
      s2 += __shfl_xor(s2, 2);
      s2 += __shfl_xor(s2, 4);
      s2 += __shfl_xor(s2, 8);
      if (lcol == 0) {
        const int grow = row_base + wr + ti * 16 + lquad * 4 + r;
        atomicAdd(&sumexp[grow], s2);
      }
    }
  }
}

// ------------------------------------------------- finalize + mean (1 block)
// loss_i = log(sumexp_i) - pos_i ; out = mean(loss)
__global__ __launch_bounds__(1024) void reduce_kernel(
    const float* __restrict__ sumexp, const float* __restrict__ pos,
    float* __restrict__ out) {
  __shared__ float ws[16];
  const int tid = threadIdx.x;
  float s = 0.f;
  const float ln2 = 0.6931471805599453f;
  for (int k = tid; k < N_ROWS; k += 1024)
    s += __builtin_amdgcn_logf(sumexp[k]) * ln2 - pos[k];
  #pragma unroll
  for (int m = 1; m < 64; m <<= 1) s += __shfl_xor(s, m);
  const int wave = tid >> 6, lane = tid & 63;
  if (lane == 0) ws[wave] = s;
  __syncthreads();
  if (wave == 0) {
    float t = (lane < 16) ? ws[lane] : 0.f;
    #pragma unroll
    for (int m = 1; m < 16; m <<= 1) t += __shfl_xor(t, m);
    if (lane == 0) out[0] = t * (1.0f / N_ROWS);
  }
}

extern "C" void kernel_launch(void* const* d_in, const int* in_sizes, int n_in,
                              void* d_out, int out_size, void* d_ws,
                              size_t ws_size, hipStream_t stream) {
  const float* z_i = (const float*)d_in[0];
  const float* z_j = (const float*)d_in[1];
  float* out = (float*)d_out;

  // workspace layout: zn (4 MB bf16) | sumexp (32 KB) | pos (32 KB)
  bf16* zn = (bf16*)d_ws;
  float* sumexp = (float*)((char*)d_ws + (size_t)N_ROWS * D_DIM * sizeof(bf16));
  float* pos = sumexp + N_ROWS;

  normalize_kernel<<<N_ROWS / 4, 256, 0, stream>>>(z_i, z_j, zn, sumexp);
  simexp_kernel<<<256, 512, 0, stream>>>(zn, sumexp, pos);
  reduce_kernel<<<1, 1024, 0, stream>>>(sumexp, pos, out);
}